// Round 10
// baseline (313.934 us; speedup 1.0000x reference)
//
#include <hip/hip_runtime.h>
#include <hip/hip_bf16.h>
#include <stdint.h>

#define B_ 8
#define S_ 1024
#define NH_ 16
#define D_ 64
#define H_ 1024
#define M_TOT (B_*S_)
#define LOG2E 1.44269504088896f

typedef __attribute__((ext_vector_type(8))) short short8;
typedef __attribute__((ext_vector_type(4))) float f32x4;
typedef __attribute__((ext_vector_type(16))) float f32x16;

#if __has_builtin(__builtin_amdgcn_exp2f)
#define EXP2(x) __builtin_amdgcn_exp2f(x)
#else
#define EXP2(x) __expf((x) * 0.69314718056f)
#endif

static __device__ __forceinline__ unsigned short f2bf(float f) {
  union { float f; unsigned u; } c; c.f = f;
  unsigned u = c.u;
  return (unsigned short)((u + 0x7fffu + ((u >> 16) & 1u)) >> 16);
}

static __device__ __forceinline__ void gld_lds16(void* lds, const void* g) {
  __builtin_amdgcn_global_load_lds((const __attribute__((address_space(1))) unsigned*)g,
                                   (__attribute__((address_space(3))) unsigned*)lds, 16, 0, 0);
}

#define WAIT_LGKM0() asm volatile("s_waitcnt lgkmcnt(0)" ::: "memory")
#define WAIT_VM(n)   asm volatile("s_waitcnt vmcnt(" #n ")" ::: "memory")
#define SBAR()       __builtin_amdgcn_s_barrier()
#define SCHED0()     __builtin_amdgcn_sched_barrier(0)
#define PRIO1()      __builtin_amdgcn_s_setprio(1)
#define PRIO0()      __builtin_amdgcn_s_setprio(0)

// ---------------- kernel 1: f32 -> bf16 conversion (X and the 3 weights) ----
__global__ void cvt_f32_bf16(const float* __restrict__ X,
                             const float* __restrict__ Wq,
                             const float* __restrict__ Wk,
                             const float* __restrict__ Wv,
                             unsigned short* __restrict__ Xbf,
                             unsigned short* __restrict__ Wbf) {
  const long long NX = (long long)M_TOT * H_;
  const long long NW = (long long)H_ * H_;
  long long t = (long long)blockIdx.x * blockDim.x + threadIdx.x;
  const long long stride = (long long)gridDim.x * blockDim.x;
  const long long total4 = (NX + 3 * NW) >> 2;
  for (; t < total4; t += stride) {
    long long e = t << 2;
    const float* src; unsigned short* dst;
    if (e < NX) { src = X + e; dst = Xbf + e; }
    else {
      long long r = e - NX;
      int w = (int)(r / NW);
      long long o = r - (long long)w * NW;
      src = (w == 0 ? Wq : (w == 1 ? Wk : Wv)) + o;
      dst = Wbf + (long long)w * NW + o;
    }
    float4 v = *(const float4*)src;
    ushort4 u;
    u.x = f2bf(v.x); u.y = f2bf(v.y); u.z = f2bf(v.z); u.w = f2bf(v.w);
    *(ushort4*)dst = u;
  }
}

// ---------------- kernel 2: QKV GEMM (R9 verbatim — 4-phase counted vmcnt) -
#define QBM 256
#define QBN 256
#define QBK 64
#define REG_B 32768
#define BUFSZ 65536

#define MMQ(I0, J0, AF, BF)                                               \
  _Pragma("unroll")                                                       \
  for (int a_ = 0; a_ < 4; ++a_)                                          \
    _Pragma("unroll")                                                     \
    for (int b_ = 0; b_ < 2; ++b_)                                        \
      _Pragma("unroll")                                                   \
      for (int k_ = 0; k_ < 2; ++k_)                                      \
        acc[(I0) + a_][(J0) + b_] = __builtin_amdgcn_mfma_f32_16x16x32_bf16( \
            AF[a_][k_], BF[b_][k_], acc[(I0) + a_][(J0) + b_], 0, 0, 0);

#define RD_A(BUF, MS)                                                     \
  _Pragma("unroll")                                                       \
  for (int f_ = 0; f_ < 4; ++f_)                                          \
    _Pragma("unroll")                                                     \
    for (int k_ = 0; k_ < 2; ++k_) A[f_][k_] = rdA(BUF, MS, f_, k_);

#define RD_B(DST, BUF, NS)                                                \
  _Pragma("unroll")                                                       \
  for (int f_ = 0; f_ < 2; ++f_)                                          \
    _Pragma("unroll")                                                     \
    for (int k_ = 0; k_ < 2; ++k_) DST[f_][k_] = rdB(BUF, NS, f_, k_);

__global__ __launch_bounds__(512, 1) void qkv_gemm(
    const unsigned short* __restrict__ Xbf,
    const unsigned short* __restrict__ Wbf,
    const float* __restrict__ bq, const float* __restrict__ bk,
    const float* __restrict__ bv,
    unsigned short* __restrict__ Qo, unsigned short* __restrict__ Ko,
    unsigned short* __restrict__ Vt) {
  __shared__ char lds[2 * BUFSZ];   // 128 KB

  const int tid = threadIdx.x;
  const int w = tid >> 6;
  const int l = tid & 63;
  const int lrow = l & 15, lgrp = l >> 4;
  const int wm = w >> 2, wn = w & 3;

  const int orig = blockIdx.x;          // 0..383
  const int xcd = orig & 7;
  const int slot = orig >> 3;           // 0..47
  const int nz = slot >> 2;             // 0..11
  const int mtile = (xcd * 4 + (slot & 3)) * QBM;
  const int ntile = (nz & 3) * QBN;
  const int z = nz >> 2;

  const unsigned short* Wz = Wbf + (long long)z * H_ * H_;

  const int srow = l >> 3;
  const int sslot = l & 7;
  auto stageReg = [&](char* buf, int region, int half, int k0) {
    #pragma unroll
    for (int jj = 0; jj < 2; ++jj) {
      int j = w * 2 + jj;                       // 0..15
      int row = half * 128 + j * 8 + srow;
      int so = (sslot ^ (row & 7)) * 8;
      if (region == 0)
        gld_lds16(buf + (half * 16 + j) * 1024,
                  Xbf + (long long)(mtile + row) * H_ + k0 + so);
      else
        gld_lds16(buf + REG_B + (half * 16 + j) * 1024,
                  Wz + (long long)(ntile + row) * H_ + k0 + so);
    }
  };
  auto stageOpA = [&](char* buf, int half, int k0) { stageReg(buf, (z == 2) ? 1 : 0, half, k0); };
  auto stageOpB = [&](char* buf, int half, int k0) { stageReg(buf, (z == 2) ? 0 : 1, half, k0); };

  const int offA = (z == 2) ? REG_B : 0;
  const int offB = (z == 2) ? 0 : REG_B;
  auto rdA = [&](const char* buf, int ms, int fi, int ks) -> short8 {
    int r = ms * 128 + wm * 64 + fi * 16 + lrow;
    return *(const short8*)(buf + offA + r * 128 + (((ks * 4 + lgrp) ^ (r & 7)) * 16));
  };
  auto rdB = [&](const char* buf, int ns, int fj, int ks) -> short8 {
    int r = ns * 128 + wn * 32 + fj * 16 + lrow;
    return *(const short8*)(buf + offB + r * 128 + (((ks * 4 + lgrp) ^ (r & 7)) * 16));
  };

  f32x4 acc[8][4];
  f32x4 zero = {0.f, 0.f, 0.f, 0.f};
  #pragma unroll
  for (int a = 0; a < 8; ++a)
    #pragma unroll
    for (int c = 0; c < 4; ++c) acc[a][c] = zero;

  short8 A[4][2], B0[2][2], B1[2][2];

  stageOpA(lds, 0, 0);
  stageOpB(lds, 0, 0);
  stageOpB(lds, 1, 0);
  stageOpA(lds, 1, 0);
  stageOpA(lds + BUFSZ, 0, QBK);
  SCHED0(); WAIT_VM(6); SCHED0();
  SBAR();

  #pragma unroll 1
  for (int t = 0; t < 15; ++t) {
    char* bc = lds + ((t & 1) ? BUFSZ : 0);
    char* bn = lds + ((t & 1) ? 0 : BUFSZ);
    const int k1 = (t + 1) * QBK;
    const int k2 = (t + 2) * QBK;
    const bool st2 = (t + 2 < 16);

    RD_A(bc, 0);
    RD_B(B0, bc, 0);
    stageOpB(bn, 0, k1);
    WAIT_LGKM0(); SCHED0();
    PRIO1(); MMQ(0, 0, A, B0); PRIO0();
    SCHED0(); WAIT_VM(6); SCHED0();
    SBAR();

    RD_B(B1, bc, 1);
    stageOpB(bn, 1, k1);
    WAIT_LGKM0(); SCHED0();
    PRIO1(); MMQ(0, 2, A, B1); PRIO0();
    SCHED0(); WAIT_VM(6); SCHED0();
    SBAR();

    RD_A(bc, 1);
    stageOpA(bn, 1, k1);
    WAIT_LGKM0(); SCHED0();
    PRIO1(); MMQ(4, 2, A, B1); PRIO0();
    SCHED0(); WAIT_VM(6); SCHED0();
    SBAR();

    if (st2) stageOpA(bc, 0, k2);
    PRIO1(); MMQ(4, 0, A, B0); PRIO0();
    SCHED0(); WAIT_VM(6); SCHED0();
    SBAR();
  }

  SCHED0(); WAIT_VM(0); SCHED0();
  SBAR();
  {
    char* bc = lds + BUFSZ;
    RD_A(bc, 0);
    RD_B(B0, bc, 0);
    WAIT_LGKM0(); SCHED0();
    PRIO1(); MMQ(0, 0, A, B0); PRIO0();
    RD_B(B1, bc, 1);
    WAIT_LGKM0(); SCHED0();
    PRIO1(); MMQ(0, 2, A, B1); PRIO0();
    RD_A(bc, 1);
    WAIT_LGKM0(); SCHED0();
    PRIO1(); MMQ(4, 2, A, B1); MMQ(4, 0, A, B0); PRIO0();
  }

  const float* bias = (z == 0) ? bq : (z == 1) ? bk : bv;
  if (z != 2) {
    unsigned short* O = (z == 0) ? Qo : Ko;
    #pragma unroll
    for (int nj = 0; nj < 4; ++nj) {
      int n = ntile + (nj >> 1) * 128 + wn * 32 + (nj & 1) * 16 + lrow;
      float bv_ = bias[n];
      int h = n >> 6, d = n & 63;
      #pragma unroll
      for (int mi = 0; mi < 8; ++mi)
        #pragma unroll
        for (int r = 0; r < 4; ++r) {
          int m = mtile + (mi >> 2) * 128 + wm * 64 + (mi & 3) * 16 + lgrp * 4 + r;
          float val = acc[mi][nj][r] + bv_;
          if (z == 0) val *= 0.125f * LOG2E;
          int b = m >> 10, s = m & 1023;
          O[(((long long)(b * NH_ + h)) * S_ + s) * D_ + d] = f2bf(val);
        }
    }
  } else {
    #pragma unroll
    for (int mi = 0; mi < 8; ++mi)
      #pragma unroll
      for (int r = 0; r < 4; ++r) {
        int nfull = ntile + (mi >> 2) * 128 + wm * 64 + (mi & 3) * 16 + lgrp * 4 + r;
        float bv_ = bias[nfull];
        int h = nfull >> 6, d = nfull & 63;
        #pragma unroll
        for (int nj = 0; nj < 4; ++nj) {
          int mfull = mtile + (nj >> 1) * 128 + wn * 32 + (nj & 1) * 16 + lrow;
          float val = acc[mi][nj][r] + bv_;
          int b = mfull >> 10, s = mfull & 1023;
          Vt[(((long long)(b * NH_ + h)) * D_ + d) * S_ + s] = f2bf(val);
        }
      }
  }
}

// ---------------- kernel 3: fused flash attention (hi-occupancy, fixed-max) -
// depth-1 dbuf (2x16KB) + 4KB pre-transformed mask = 36KB LDS -> 4 blocks/CU
// = 16 waves/CU. Fixed-max softmax: P = exp2(score*log2e + mask*log2e - 12)
// (constant shift cancels in the final division -> mathematically exact).
// No max tree, no m_run, no rescale.
__global__ __launch_bounds__(256, 4) void attn_fused(
    const unsigned short* __restrict__ Qbf,
    const unsigned short* __restrict__ Kbf,
    const unsigned short* __restrict__ Vtb,
    const float* __restrict__ mask,
    float* __restrict__ out) {
  __shared__ char lds[2 * 16384 + 4096];      // K|V dbuf, then mask row
  char* ldsM = lds + 32768;
  const int tid = threadIdx.x, w = tid >> 6, l = tid & 63;
  const int l31 = l & 31, h = l >> 5;

  const int lid = blockIdx.x;                 // 0..511
  const int xcd = lid & 7, k8 = lid >> 3;
  const int bh = xcd * 16 + (k8 >> 2);
  const int qt = k8 & 3;
  const int b = bh >> 4, hd = bh & 15;
  const int q0 = qt * 256 + w * 64;

  const unsigned short* Kg = Kbf + (long long)bh * S_ * D_;
  const unsigned short* Vg = Vtb + (long long)bh * D_ * S_;
  const float* mrow = mask + b * S_;

  auto stageKV = [&](int kt, char* buf) {
    const int key0 = kt * 64;
    #pragma unroll
    for (int t = 0; t < 2; ++t) {
      int j = w * 2 + t;
      int row = j * 8 + (l >> 3);
      int so = ((l & 7) ^ (row & 7)) * 8;
      gld_lds16(buf + j * 1024,        Kg + (long long)(key0 + row) * D_ + so);
      gld_lds16(buf + 8192 + j * 1024, Vg + (long long)row * S_ + key0 + so);
    }
  };

  // ---- prologue: qf loads, mask pre-transform (m*log2e - 12), stage tile 0
  short8 qf[2][4];
  #pragma unroll
  for (int qb = 0; qb < 2; ++qb)
    #pragma unroll
    for (int ks = 0; ks < 4; ++ks)
      qf[qb][ks] = *(const short8*)(Qbf + ((long long)bh * S_ + q0 + qb * 32 + l31) * D_ + ks * 16 + 8 * h);
  {
    float4 mv = *(const float4*)(mrow + tid * 4);
    f32x4 mt;
    mt[0] = mv.x * LOG2E - 12.f;
    mt[1] = mv.y * LOG2E - 12.f;
    mt[2] = mv.z * LOG2E - 12.f;
    mt[3] = mv.w * LOG2E - 12.f;
    *(f32x4*)(ldsM + tid * 16) = mt;
  }
  stageKV(0, lds);
  SCHED0(); WAIT_VM(0); SCHED0();   // qf + tile0 resident
  __syncthreads();                   // also drains the mask ds_write

  f32x16 acc[2][2];
  #pragma unroll
  for (int db = 0; db < 2; ++db)
    #pragma unroll
    for (int qb = 0; qb < 2; ++qb)
      #pragma unroll
      for (int r = 0; r < 16; ++r) acc[db][qb][r] = 0.f;
  float l_run[2] = {0.f, 0.f};

  #pragma unroll 1
  for (int kt = 0; kt < S_ / 64; ++kt) {
    char* ldsK = lds + (kt & 1) * 16384;
    char* ldsV = ldsK + 8192;
    const int key0 = kt * 64;
    const bool st = (kt + 1 < S_ / 64);

    if (st) stageKV(kt + 1, lds + ((kt + 1) & 1) * 16384);

    // ---- QK^T (swapped): sc[kb][qb] = S^T
    f32x16 sc[2][2];
    #pragma unroll
    for (int kb = 0; kb < 2; ++kb)
      #pragma unroll
      for (int qb = 0; qb < 2; ++qb)
        #pragma unroll
        for (int r = 0; r < 16; ++r) sc[kb][qb][r] = 0.f;

    #pragma unroll
    for (int kb = 0; kb < 2; ++kb) {
      short8 kf[4];
      #pragma unroll
      for (int ks = 0; ks < 4; ++ks) {
        int row = kb * 32 + l31;
        int g = (2 * ks + h) ^ (row & 7);
        kf[ks] = *(const short8*)(ldsK + row * 128 + g * 16);
      }
      PRIO1();
      #pragma unroll
      for (int qb = 0; qb < 2; ++qb)
        #pragma unroll
        for (int ks = 0; ks < 4; ++ks)
          sc[kb][qb] = __builtin_amdgcn_mfma_f32_32x32x16_bf16(
              kf[ks], qf[qb][ks], sc[kb][qb], 0, 0, 0);
      PRIO0();
    }

    // ---- fixed-max softmax: P = exp2(sc + mpre), sum tree only
    short8 pfrag[2][4];
    #pragma unroll
    for (int qb = 0; qb < 2; ++qb) {
      float sv[32];
      #pragma unroll
      for (int kb = 0; kb < 2; ++kb)
        #pragma unroll
        for (int rg = 0; rg < 4; ++rg) {
          f32x4 m4 = *(const f32x4*)(ldsM + (key0 + kb * 32 + rg * 8 + 4 * h) * 4);
          #pragma unroll
          for (int c = 0; c < 4; ++c)
            sv[kb * 16 + rg * 4 + c] = EXP2(sc[kb][qb][rg * 4 + c] + m4[c]);
        }
      float r16[16];
      #pragma unroll
      for (int i = 0; i < 16; ++i) r16[i] = sv[i] + sv[i + 16];
      #pragma unroll
      for (int i = 0; i < 8; ++i) r16[i] = r16[i] + r16[i + 8];
      #pragma unroll
      for (int i = 0; i < 4; ++i) r16[i] = r16[i] + r16[i + 4];
      float ps = (r16[0] + r16[1]) + (r16[2] + r16[3]);
      ps += __shfl_xor(ps, 32);
      l_run[qb] += ps;

      unsigned Wd[8][2];
      #pragma unroll
      for (int j = 0; j < 8; ++j) {
        int base = (j >> 2) * 16 + (j & 3) * 4;
        asm("v_cvt_pk_bf16_f32 %0, %1, %2" : "=v"(Wd[j][0]) : "v"(sv[base + 0]), "v"(sv[base + 1]));
        asm("v_cvt_pk_bf16_f32 %0, %1, %2" : "=v"(Wd[j][1]) : "v"(sv[base + 2]), "v"(sv[base + 3]));
      }
      #pragma unroll
      for (int ks = 0; ks < 4; ++ks) {
        unsigned s0 = h ? Wd[2 * ks][0] : Wd[2 * ks + 1][0];
        unsigned s1 = h ? Wd[2 * ks][1] : Wd[2 * ks + 1][1];
        unsigned r0 = __shfl_xor(s0, 32);
        unsigned r1 = __shfl_xor(s1, 32);
        unsigned o0 = h ? Wd[2 * ks + 1][0] : Wd[2 * ks][0];
        unsigned o1 = h ? Wd[2 * ks + 1][1] : Wd[2 * ks][1];
        union { unsigned u[4]; short8 s; } fu;
        fu.u[0] = h ? r0 : o0;
        fu.u[1] = h ? r1 : o1;
        fu.u[2] = h ? o0 : r0;
        fu.u[3] = h ? o1 : r1;
        pfrag[qb][ks] = fu.s;
      }
    }

    // ---- PV (swapped)
    #pragma unroll
    for (int db = 0; db < 2; ++db) {
      short8 vf[4];
      #pragma unroll
      for (int ks = 0; ks < 4; ++ks) {
        int row = db * 32 + l31;
        int g = (2 * ks + h) ^ (row & 7);
        vf[ks] = *(const short8*)(ldsV + row * 128 + g * 16);
      }
      PRIO1();
      #pragma unroll
      for (int qb = 0; qb < 2; ++qb)
        #pragma unroll
        for (int ks = 0; ks < 4; ++ks)
          acc[db][qb] = __builtin_amdgcn_mfma_f32_32x32x16_bf16(
              vf[ks], pfrag[qb][ks], acc[db][qb], 0, 0, 0);
      PRIO0();
    }

    // ---- tile boundary: drain stage of t+1, flip buffers
    if (st) { SCHED0(); WAIT_VM(0); SCHED0(); SBAR(); }
  }

  // ---- epilogue
  #pragma unroll
  for (int qb = 0; qb < 2; ++qb) {
    float inv = 1.0f / l_run[qb];
    int q = q0 + qb * 32 + l31;
    float* orow = out + ((long long)b * S_ + q) * H_ + hd * D_;
    #pragma unroll
    for (int db = 0; db < 2; ++db)
      #pragma unroll
      for (int rg = 0; rg < 4; ++rg) {
        f32x4 v4;
        #pragma unroll
        for (int c = 0; c < 4; ++c) v4[c] = acc[db][qb][rg * 4 + c] * inv;
        *(f32x4*)(orow + db * 32 + rg * 8 + 4 * h) = v4;
      }
  }
}

// ---------------- launcher -------------------------------------------------
extern "C" void kernel_launch(void* const* d_in, const int* in_sizes, int n_in,
                              void* d_out, int out_size, void* d_ws, size_t ws_size,
                              hipStream_t stream) {
  const float* X    = (const float*)d_in[0];
  const float* mask = (const float*)d_in[1];
  const float* Wq   = (const float*)d_in[2];
  const float* bq   = (const float*)d_in[3];
  const float* Wk   = (const float*)d_in[4];
  const float* bk   = (const float*)d_in[5];
  const float* Wv   = (const float*)d_in[6];
  const float* bv   = (const float*)d_in[7];
  float* out = (float*)d_out;

  char* ws = (char*)d_ws;
  unsigned short* Xbf = (unsigned short*)ws;                 // 16 MB
  unsigned short* Wbf = (unsigned short*)(ws + 16777216);    //  6 MB
  unsigned short* Qb  = (unsigned short*)(ws + 23068672);    // 16 MB
  unsigned short* Kb  = (unsigned short*)(ws + 39845888);    // 16 MB
  unsigned short* Vt  = (unsigned short*)(ws + 56623104);    // 16 MB

  hipLaunchKernelGGL(cvt_f32_bf16, dim3(2048), dim3(256), 0, stream,
                     X, Wq, Wk, Wv, Xbf, Wbf);
  hipLaunchKernelGGL(qkv_gemm, dim3(384), dim3(512), 0, stream,
                     Xbf, Wbf, bq, bk, bv, Qb, Kb, Vt);
  hipLaunchKernelGGL(attn_fused, dim3(512), dim3(256), 0, stream,
                     Qb, Kb, Vt, mask, out);
}

// Round 11
// 121.860 us; speedup vs baseline: 2.5762x; 2.5762x over previous
//
#include <hip/hip_runtime.h>
#include <hip/hip_bf16.h>
#include <stdint.h>

#define B_ 8
#define S_ 1024
#define NH_ 16
#define D_ 64
#define H_ 1024
#define M_TOT (B_*S_)
#define LOG2E 1.44269504088896f

typedef __attribute__((ext_vector_type(8))) short short8;
typedef __attribute__((ext_vector_type(4))) float f32x4;
typedef __attribute__((ext_vector_type(16))) float f32x16;

#if __has_builtin(__builtin_amdgcn_exp2f)
#define EXP2(x) __builtin_amdgcn_exp2f(x)
#else
#define EXP2(x) __expf((x) * 0.69314718056f)
#endif

static __device__ __forceinline__ unsigned short f2bf(float f) {
  union { float f; unsigned u; } c; c.f = f;
  unsigned u = c.u;
  return (unsigned short)((u + 0x7fffu + ((u >> 16) & 1u)) >> 16);
}

static __device__ __forceinline__ void gld_lds16(void* lds, const void* g) {
  __builtin_amdgcn_global_load_lds((const __attribute__((address_space(1))) unsigned*)g,
                                   (__attribute__((address_space(3))) unsigned*)lds, 16, 0, 0);
}

#define WAIT_LGKM0() asm volatile("s_waitcnt lgkmcnt(0)" ::: "memory")
#define WAIT_VM(n)   asm volatile("s_waitcnt vmcnt(" #n ")" ::: "memory")
#define SBAR()       __builtin_amdgcn_s_barrier()
#define SCHED0()     __builtin_amdgcn_sched_barrier(0)
#define PRIO1()      __builtin_amdgcn_s_setprio(1)
#define PRIO0()      __builtin_amdgcn_s_setprio(0)

// ---------------- kernel 1: f32 -> bf16 conversion (X and the 3 weights) ----
__global__ void cvt_f32_bf16(const float* __restrict__ X,
                             const float* __restrict__ Wq,
                             const float* __restrict__ Wk,
                             const float* __restrict__ Wv,
                             unsigned short* __restrict__ Xbf,
                             unsigned short* __restrict__ Wbf) {
  const long long NX = (long long)M_TOT * H_;
  const long long NW = (long long)H_ * H_;
  long long t = (long long)blockIdx.x * blockDim.x + threadIdx.x;
  const long long stride = (long long)gridDim.x * blockDim.x;
  const long long total4 = (NX + 3 * NW) >> 2;
  for (; t < total4; t += stride) {
    long long e = t << 2;
    const float* src; unsigned short* dst;
    if (e < NX) { src = X + e; dst = Xbf + e; }
    else {
      long long r = e - NX;
      int w = (int)(r / NW);
      long long o = r - (long long)w * NW;
      src = (w == 0 ? Wq : (w == 1 ? Wk : Wv)) + o;
      dst = Wbf + (long long)w * NW + o;
    }
    float4 v = *(const float4*)src;
    ushort4 u;
    u.x = f2bf(v.x); u.y = f2bf(v.y); u.z = f2bf(v.z); u.w = f2bf(v.w);
    *(ushort4*)dst = u;
  }
}

// ---------------- kernel 2: QKV GEMM (R9 verbatim — 4-phase counted vmcnt) -
#define QBM 256
#define QBN 256
#define QBK 64
#define REG_B 32768
#define BUFSZ 65536

#define MMQ(I0, J0, AF, BF)                                               \
  _Pragma("unroll")                                                       \
  for (int a_ = 0; a_ < 4; ++a_)                                          \
    _Pragma("unroll")                                                     \
    for (int b_ = 0; b_ < 2; ++b_)                                        \
      _Pragma("unroll")                                                   \
      for (int k_ = 0; k_ < 2; ++k_)                                      \
        acc[(I0) + a_][(J0) + b_] = __builtin_amdgcn_mfma_f32_16x16x32_bf16( \
            AF[a_][k_], BF[b_][k_], acc[(I0) + a_][(J0) + b_], 0, 0, 0);

#define RD_A(BUF, MS)                                                     \
  _Pragma("unroll")                                                       \
  for (int f_ = 0; f_ < 4; ++f_)                                          \
    _Pragma("unroll")                                                     \
    for (int k_ = 0; k_ < 2; ++k_) A[f_][k_] = rdA(BUF, MS, f_, k_);

#define RD_B(DST, BUF, NS)                                                \
  _Pragma("unroll")                                                       \
  for (int f_ = 0; f_ < 2; ++f_)                                          \
    _Pragma("unroll")                                                     \
    for (int k_ = 0; k_ < 2; ++k_) DST[f_][k_] = rdB(BUF, NS, f_, k_);

__global__ __launch_bounds__(512, 1) void qkv_gemm(
    const unsigned short* __restrict__ Xbf,
    const unsigned short* __restrict__ Wbf,
    const float* __restrict__ bq, const float* __restrict__ bk,
    const float* __restrict__ bv,
    unsigned short* __restrict__ Qo, unsigned short* __restrict__ Ko,
    unsigned short* __restrict__ Vt) {
  __shared__ char lds[2 * BUFSZ];   // 128 KB

  const int tid = threadIdx.x;
  const int w = tid >> 6;
  const int l = tid & 63;
  const int lrow = l & 15, lgrp = l >> 4;
  const int wm = w >> 2, wn = w & 3;

  const int orig = blockIdx.x;          // 0..383
  const int xcd = orig & 7;
  const int slot = orig >> 3;           // 0..47
  const int nz = slot >> 2;             // 0..11
  const int mtile = (xcd * 4 + (slot & 3)) * QBM;
  const int ntile = (nz & 3) * QBN;
  const int z = nz >> 2;

  const unsigned short* Wz = Wbf + (long long)z * H_ * H_;

  const int srow = l >> 3;
  const int sslot = l & 7;
  auto stageReg = [&](char* buf, int region, int half, int k0) {
    #pragma unroll
    for (int jj = 0; jj < 2; ++jj) {
      int j = w * 2 + jj;                       // 0..15
      int row = half * 128 + j * 8 + srow;
      int so = (sslot ^ (row & 7)) * 8;
      if (region == 0)
        gld_lds16(buf + (half * 16 + j) * 1024,
                  Xbf + (long long)(mtile + row) * H_ + k0 + so);
      else
        gld_lds16(buf + REG_B + (half * 16 + j) * 1024,
                  Wz + (long long)(ntile + row) * H_ + k0 + so);
    }
  };
  auto stageOpA = [&](char* buf, int half, int k0) { stageReg(buf, (z == 2) ? 1 : 0, half, k0); };
  auto stageOpB = [&](char* buf, int half, int k0) { stageReg(buf, (z == 2) ? 0 : 1, half, k0); };

  const int offA = (z == 2) ? REG_B : 0;
  const int offB = (z == 2) ? 0 : REG_B;
  auto rdA = [&](const char* buf, int ms, int fi, int ks) -> short8 {
    int r = ms * 128 + wm * 64 + fi * 16 + lrow;
    return *(const short8*)(buf + offA + r * 128 + (((ks * 4 + lgrp) ^ (r & 7)) * 16));
  };
  auto rdB = [&](const char* buf, int ns, int fj, int ks) -> short8 {
    int r = ns * 128 + wn * 32 + fj * 16 + lrow;
    return *(const short8*)(buf + offB + r * 128 + (((ks * 4 + lgrp) ^ (r & 7)) * 16));
  };

  f32x4 acc[8][4];
  f32x4 zero = {0.f, 0.f, 0.f, 0.f};
  #pragma unroll
  for (int a = 0; a < 8; ++a)
    #pragma unroll
    for (int c = 0; c < 4; ++c) acc[a][c] = zero;

  short8 A[4][2], B0[2][2], B1[2][2];

  stageOpA(lds, 0, 0);
  stageOpB(lds, 0, 0);
  stageOpB(lds, 1, 0);
  stageOpA(lds, 1, 0);
  stageOpA(lds + BUFSZ, 0, QBK);
  SCHED0(); WAIT_VM(6); SCHED0();
  SBAR();

  #pragma unroll 1
  for (int t = 0; t < 15; ++t) {
    char* bc = lds + ((t & 1) ? BUFSZ : 0);
    char* bn = lds + ((t & 1) ? 0 : BUFSZ);
    const int k1 = (t + 1) * QBK;
    const int k2 = (t + 2) * QBK;
    const bool st2 = (t + 2 < 16);

    RD_A(bc, 0);
    RD_B(B0, bc, 0);
    stageOpB(bn, 0, k1);
    WAIT_LGKM0(); SCHED0();
    PRIO1(); MMQ(0, 0, A, B0); PRIO0();
    SCHED0(); WAIT_VM(6); SCHED0();
    SBAR();

    RD_B(B1, bc, 1);
    stageOpB(bn, 1, k1);
    WAIT_LGKM0(); SCHED0();
    PRIO1(); MMQ(0, 2, A, B1); PRIO0();
    SCHED0(); WAIT_VM(6); SCHED0();
    SBAR();

    RD_A(bc, 1);
    stageOpA(bn, 1, k1);
    WAIT_LGKM0(); SCHED0();
    PRIO1(); MMQ(4, 2, A, B1); PRIO0();
    SCHED0(); WAIT_VM(6); SCHED0();
    SBAR();

    if (st2) stageOpA(bc, 0, k2);
    PRIO1(); MMQ(4, 0, A, B0); PRIO0();
    SCHED0(); WAIT_VM(6); SCHED0();
    SBAR();
  }

  SCHED0(); WAIT_VM(0); SCHED0();
  SBAR();
  {
    char* bc = lds + BUFSZ;
    RD_A(bc, 0);
    RD_B(B0, bc, 0);
    WAIT_LGKM0(); SCHED0();
    PRIO1(); MMQ(0, 0, A, B0); PRIO0();
    RD_B(B1, bc, 1);
    WAIT_LGKM0(); SCHED0();
    PRIO1(); MMQ(0, 2, A, B1); PRIO0();
    RD_A(bc, 1);
    WAIT_LGKM0(); SCHED0();
    PRIO1(); MMQ(4, 2, A, B1); MMQ(4, 0, A, B0); PRIO0();
  }

  const float* bias = (z == 0) ? bq : (z == 1) ? bk : bv;
  if (z != 2) {
    unsigned short* O = (z == 0) ? Qo : Ko;
    #pragma unroll
    for (int nj = 0; nj < 4; ++nj) {
      int n = ntile + (nj >> 1) * 128 + wn * 32 + (nj & 1) * 16 + lrow;
      float bv_ = bias[n];
      int h = n >> 6, d = n & 63;
      #pragma unroll
      for (int mi = 0; mi < 8; ++mi)
        #pragma unroll
        for (int r = 0; r < 4; ++r) {
          int m = mtile + (mi >> 2) * 128 + wm * 64 + (mi & 3) * 16 + lgrp * 4 + r;
          float val = acc[mi][nj][r] + bv_;
          if (z == 0) val *= 0.125f * LOG2E;
          int b = m >> 10, s = m & 1023;
          O[(((long long)(b * NH_ + h)) * S_ + s) * D_ + d] = f2bf(val);
        }
    }
  } else {
    #pragma unroll
    for (int mi = 0; mi < 8; ++mi)
      #pragma unroll
      for (int r = 0; r < 4; ++r) {
        int nfull = ntile + (mi >> 2) * 128 + wm * 64 + (mi & 3) * 16 + lgrp * 4 + r;
        float bv_ = bias[nfull];
        int h = nfull >> 6, d = nfull & 63;
        #pragma unroll
        for (int nj = 0; nj < 4; ++nj) {
          int mfull = mtile + (nj >> 1) * 128 + wn * 32 + (nj & 1) * 16 + lrow;
          float val = acc[mi][nj][r] + bv_;
          int b = mfull >> 10, s = mfull & 1023;
          Vt[(((long long)(b * NH_ + h)) * D_ + d) * S_ + s] = f2bf(val);
        }
      }
  }
}

// ---------------- kernel 3: attention v3 — 32 q-rows/wave, grid 1024 -------
// 8 q-tiles of 128 rows per bh; block = 4 waves x 32 q rows. Depth-1 dbuf
// (2x16KB) + 4KB mask = 36KB LDS -> 4 blocks/CU resident (grid 1024).
// Fixed-max softmax (validated R10): P = exp2(sc + mask*log2e - 12); the
// constant shift cancels in the final division. Halved per-wave register
// state (acc[2], sc[2]) keeps arch VGPR < 128 so HW occupancy = 4 blocks/CU
// WITHOUT a forcing launch_bounds (R10 lesson: min-occupancy bound caused
// a 64-reg cap and 1.16GB scratch spill).
__global__ __launch_bounds__(256, 2) void attn_fused(
    const unsigned short* __restrict__ Qbf,
    const unsigned short* __restrict__ Kbf,
    const unsigned short* __restrict__ Vtb,
    const float* __restrict__ mask,
    float* __restrict__ out) {
  __shared__ char lds[2 * 16384 + 4096];      // K|V dbuf, then mask row
  char* ldsM = lds + 32768;
  const int tid = threadIdx.x, w = tid >> 6, l = tid & 63;
  const int l31 = l & 31, h = l >> 5;

  const int lid = blockIdx.x;                 // 0..1023
  const int xcd = lid & 7, k = lid >> 3;      // all 8 q-tiles of a bh -> 1 XCD
  const int bh = xcd * 16 + (k >> 3);
  const int qt = k & 7;
  const int b = bh >> 4, hd = bh & 15;
  const int q0 = qt * 128 + w * 32;

  const unsigned short* Kg = Kbf + (long long)bh * S_ * D_;
  const unsigned short* Vg = Vtb + (long long)bh * D_ * S_;
  const float* mrow = mask + b * S_;

  auto stageKV = [&](int kt, char* buf) {
    const int key0 = kt * 64;
    #pragma unroll
    for (int t = 0; t < 2; ++t) {
      int j = w * 2 + t;
      int row = j * 8 + (l >> 3);
      int so = ((l & 7) ^ (row & 7)) * 8;
      gld_lds16(buf + j * 1024,        Kg + (long long)(key0 + row) * D_ + so);
      gld_lds16(buf + 8192 + j * 1024, Vg + (long long)row * S_ + key0 + so);
    }
  };

  // ---- prologue: qf, mask pre-transform, stage tile 0
  short8 qf[4];
  #pragma unroll
  for (int ks = 0; ks < 4; ++ks)
    qf[ks] = *(const short8*)(Qbf + ((long long)bh * S_ + q0 + l31) * D_ + ks * 16 + 8 * h);
  {
    float4 mv = *(const float4*)(mrow + tid * 4);
    f32x4 mt;
    mt[0] = mv.x * LOG2E - 12.f;
    mt[1] = mv.y * LOG2E - 12.f;
    mt[2] = mv.z * LOG2E - 12.f;
    mt[3] = mv.w * LOG2E - 12.f;
    *(f32x4*)(ldsM + tid * 16) = mt;
  }
  stageKV(0, lds);
  SCHED0(); WAIT_VM(0); SCHED0();
  __syncthreads();                   // mask ds_write + tile0 published

  f32x16 acc[2];
  #pragma unroll
  for (int db = 0; db < 2; ++db)
    #pragma unroll
    for (int r = 0; r < 16; ++r) acc[db][r] = 0.f;
  float l_run = 0.f;

  #pragma unroll 1
  for (int kt = 0; kt < S_ / 64; ++kt) {
    char* ldsK = lds + (kt & 1) * 16384;
    char* ldsV = ldsK + 8192;
    const int key0 = kt * 64;
    const bool st = (kt + 1 < S_ / 64);

    if (st) stageKV(kt + 1, lds + ((kt + 1) & 1) * 16384);

    // ---- QK^T (swapped): sc[kb] = S^T block, lane owns q col l31
    f32x16 sc[2];
    #pragma unroll
    for (int kb = 0; kb < 2; ++kb)
      #pragma unroll
      for (int r = 0; r < 16; ++r) sc[kb][r] = 0.f;

    #pragma unroll
    for (int kb = 0; kb < 2; ++kb) {
      short8 kf[4];
      #pragma unroll
      for (int ks = 0; ks < 4; ++ks) {
        int row = kb * 32 + l31;
        int g = (2 * ks + h) ^ (row & 7);
        kf[ks] = *(const short8*)(ldsK + row * 128 + g * 16);
      }
      PRIO1();
      #pragma unroll
      for (int ks = 0; ks < 4; ++ks)
        sc[kb] = __builtin_amdgcn_mfma_f32_32x32x16_bf16(
            kf[ks], qf[ks], sc[kb], 0, 0, 0);
      PRIO0();
    }

    // ---- fixed-max softmax: P = exp2(sc + mpre); sum tree only
    float sv[32];
    #pragma unroll
    for (int kb = 0; kb < 2; ++kb)
      #pragma unroll
      for (int rg = 0; rg < 4; ++rg) {
        f32x4 m4 = *(const f32x4*)(ldsM + (key0 + kb * 32 + rg * 8 + 4 * h) * 4);
        #pragma unroll
        for (int c = 0; c < 4; ++c)
          sv[kb * 16 + rg * 4 + c] = EXP2(sc[kb][rg * 4 + c] + m4[c]);
      }
    {
      float r16[16];
      #pragma unroll
      for (int i = 0; i < 16; ++i) r16[i] = sv[i] + sv[i + 16];
      #pragma unroll
      for (int i = 0; i < 8; ++i) r16[i] = r16[i] + r16[i + 8];
      #pragma unroll
      for (int i = 0; i < 4; ++i) r16[i] = r16[i] + r16[i + 4];
      float ps = (r16[0] + r16[1]) + (r16[2] + r16[3]);
      ps += __shfl_xor(ps, 32);
      l_run += ps;
    }

    // ---- pack P -> bf16 fragments (half-exchange)
    short8 pfrag[4];
    {
      unsigned Wd[8][2];
      #pragma unroll
      for (int j = 0; j < 8; ++j) {
        int base = (j >> 2) * 16 + (j & 3) * 4;
        asm("v_cvt_pk_bf16_f32 %0, %1, %2" : "=v"(Wd[j][0]) : "v"(sv[base + 0]), "v"(sv[base + 1]));
        asm("v_cvt_pk_bf16_f32 %0, %1, %2" : "=v"(Wd[j][1]) : "v"(sv[base + 2]), "v"(sv[base + 3]));
      }
      #pragma unroll
      for (int ks = 0; ks < 4; ++ks) {
        unsigned s0 = h ? Wd[2 * ks][0] : Wd[2 * ks + 1][0];
        unsigned s1 = h ? Wd[2 * ks][1] : Wd[2 * ks + 1][1];
        unsigned r0 = __shfl_xor(s0, 32);
        unsigned r1 = __shfl_xor(s1, 32);
        unsigned o0 = h ? Wd[2 * ks + 1][0] : Wd[2 * ks][0];
        unsigned o1 = h ? Wd[2 * ks + 1][1] : Wd[2 * ks][1];
        union { unsigned u[4]; short8 s; } fu;
        fu.u[0] = h ? r0 : o0;
        fu.u[1] = h ? r1 : o1;
        fu.u[2] = h ? o0 : r0;
        fu.u[3] = h ? o1 : r1;
        pfrag[ks] = fu.s;
      }
    }

    // ---- PV (swapped): acc[db] += V^T-frag x P^T-frag
    #pragma unroll
    for (int db = 0; db < 2; ++db) {
      short8 vf[4];
      #pragma unroll
      for (int ks = 0; ks < 4; ++ks) {
        int row = db * 32 + l31;
        int g = (2 * ks + h) ^ (row & 7);
        vf[ks] = *(const short8*)(ldsV + row * 128 + g * 16);
      }
      PRIO1();
      #pragma unroll
      for (int ks = 0; ks < 4; ++ks)
        acc[db] = __builtin_amdgcn_mfma_f32_32x32x16_bf16(
            vf[ks], pfrag[ks], acc[db], 0, 0, 0);
      PRIO0();
    }

    if (st) { SCHED0(); WAIT_VM(0); SCHED0(); SBAR(); }
  }

  // ---- epilogue
  {
    float inv = 1.0f / l_run;
    int q = q0 + l31;
    float* orow = out + ((long long)b * S_ + q) * H_ + hd * D_;
    #pragma unroll
    for (int db = 0; db < 2; ++db)
      #pragma unroll
      for (int rg = 0; rg < 4; ++rg) {
        f32x4 v4;
        #pragma unroll
        for (int c = 0; c < 4; ++c) v4[c] = acc[db][rg * 4 + c] * inv;
        *(f32x4*)(orow + db * 32 + rg * 8 + 4 * h) = v4;
      }
  }
}

// ---------------- launcher -------------------------------------------------
extern "C" void kernel_launch(void* const* d_in, const int* in_sizes, int n_in,
                              void* d_out, int out_size, void* d_ws, size_t ws_size,
                              hipStream_t stream) {
  const float* X    = (const float*)d_in[0];
  const float* mask = (const float*)d_in[1];
  const float* Wq   = (const float*)d_in[2];
  const float* bq   = (const float*)d_in[3];
  const float* Wk   = (const float*)d_in[4];
  const float* bk   = (const float*)d_in[5];
  const float* Wv   = (const float*)d_in[6];
  const float* bv   = (const float*)d_in[7];
  float* out = (float*)d_out;

  char* ws = (char*)d_ws;
  unsigned short* Xbf = (unsigned short*)ws;                 // 16 MB
  unsigned short* Wbf = (unsigned short*)(ws + 16777216);    //  6 MB
  unsigned short* Qb  = (unsigned short*)(ws + 23068672);    // 16 MB
  unsigned short* Kb  = (unsigned short*)(ws + 39845888);    // 16 MB
  unsigned short* Vt  = (unsigned short*)(ws + 56623104);    // 16 MB

  hipLaunchKernelGGL(cvt_f32_bf16, dim3(2048), dim3(256), 0, stream,
                     X, Wq, Wk, Wv, Xbf, Wbf);
  hipLaunchKernelGGL(qkv_gemm, dim3(384), dim3(512), 0, stream,
                     Xbf, Wbf, bq, bk, bv, Qb, Kb, Vt);
  hipLaunchKernelGGL(attn_fused, dim3(1024), dim3(256), 0, stream,
                     Qb, Kb, Vt, mask, out);
}

// Round 12
// 119.327 us; speedup vs baseline: 2.6309x; 1.0212x over previous
//
#include <hip/hip_runtime.h>
#include <hip/hip_bf16.h>
#include <stdint.h>

#define B_ 8
#define S_ 1024
#define NH_ 16
#define D_ 64
#define H_ 1024
#define M_TOT (B_*S_)
#define LOG2E 1.44269504088896f

typedef __attribute__((ext_vector_type(8))) short short8;
typedef __attribute__((ext_vector_type(4))) float f32x4;
typedef __attribute__((ext_vector_type(16))) float f32x16;

#if __has_builtin(__builtin_amdgcn_exp2f)
#define EXP2(x) __builtin_amdgcn_exp2f(x)
#else
#define EXP2(x) __expf((x) * 0.69314718056f)
#endif

static __device__ __forceinline__ unsigned short f2bf(float f) {
  union { float f; unsigned u; } c; c.f = f;
  unsigned u = c.u;
  return (unsigned short)((u + 0x7fffu + ((u >> 16) & 1u)) >> 16);
}

static __device__ __forceinline__ void gld_lds16(void* lds, const void* g) {
  __builtin_amdgcn_global_load_lds((const __attribute__((address_space(1))) unsigned*)g,
                                   (__attribute__((address_space(3))) unsigned*)lds, 16, 0, 0);
}

#define WAIT_LGKM0() asm volatile("s_waitcnt lgkmcnt(0)" ::: "memory")
#define WAIT_VM(n)   asm volatile("s_waitcnt vmcnt(" #n ")" ::: "memory")
#define SBAR()       __builtin_amdgcn_s_barrier()
#define SCHED0()     __builtin_amdgcn_sched_barrier(0)
#define PRIO1()      __builtin_amdgcn_s_setprio(1)
#define PRIO0()      __builtin_amdgcn_s_setprio(0)

// ---------------- kernel 1: f32 -> bf16 conversion (X and the 3 weights) ----
__global__ void cvt_f32_bf16(const float* __restrict__ X,
                             const float* __restrict__ Wq,
                             const float* __restrict__ Wk,
                             const float* __restrict__ Wv,
                             unsigned short* __restrict__ Xbf,
                             unsigned short* __restrict__ Wbf) {
  const long long NX = (long long)M_TOT * H_;
  const long long NW = (long long)H_ * H_;
  long long t = (long long)blockIdx.x * blockDim.x + threadIdx.x;
  const long long stride = (long long)gridDim.x * blockDim.x;
  const long long total4 = (NX + 3 * NW) >> 2;
  for (; t < total4; t += stride) {
    long long e = t << 2;
    const float* src; unsigned short* dst;
    if (e < NX) { src = X + e; dst = Xbf + e; }
    else {
      long long r = e - NX;
      int w = (int)(r / NW);
      long long o = r - (long long)w * NW;
      src = (w == 0 ? Wq : (w == 1 ? Wk : Wv)) + o;
      dst = Wbf + (long long)w * NW + o;
    }
    float4 v = *(const float4*)src;
    ushort4 u;
    u.x = f2bf(v.x); u.y = f2bf(v.y); u.z = f2bf(v.z); u.w = f2bf(v.w);
    *(ushort4*)dst = u;
  }
}

// ---------------- kernel 2: QKV GEMM (R9 verbatim — 4-phase counted vmcnt) -
#define QBM 256
#define QBN 256
#define QBK 64
#define REG_B 32768
#define BUFSZ 65536

#define MMQ(I0, J0, AF, BF)                                               \
  _Pragma("unroll")                                                       \
  for (int a_ = 0; a_ < 4; ++a_)                                          \
    _Pragma("unroll")                                                     \
    for (int b_ = 0; b_ < 2; ++b_)                                        \
      _Pragma("unroll")                                                   \
      for (int k_ = 0; k_ < 2; ++k_)                                      \
        acc[(I0) + a_][(J0) + b_] = __builtin_amdgcn_mfma_f32_16x16x32_bf16( \
            AF[a_][k_], BF[b_][k_], acc[(I0) + a_][(J0) + b_], 0, 0, 0);

#define RD_A(BUF, MS)                                                     \
  _Pragma("unroll")                                                       \
  for (int f_ = 0; f_ < 4; ++f_)                                          \
    _Pragma("unroll")                                                     \
    for (int k_ = 0; k_ < 2; ++k_) A[f_][k_] = rdA(BUF, MS, f_, k_);

#define RD_B(DST, BUF, NS)                                                \
  _Pragma("unroll")                                                       \
  for (int f_ = 0; f_ < 2; ++f_)                                          \
    _Pragma("unroll")                                                     \
    for (int k_ = 0; k_ < 2; ++k_) DST[f_][k_] = rdB(BUF, NS, f_, k_);

__global__ __launch_bounds__(512, 1) void qkv_gemm(
    const unsigned short* __restrict__ Xbf,
    const unsigned short* __restrict__ Wbf,
    const float* __restrict__ bq, const float* __restrict__ bk,
    const float* __restrict__ bv,
    unsigned short* __restrict__ Qo, unsigned short* __restrict__ Ko,
    unsigned short* __restrict__ Vt) {
  __shared__ char lds[2 * BUFSZ];   // 128 KB

  const int tid = threadIdx.x;
  const int w = tid >> 6;
  const int l = tid & 63;
  const int lrow = l & 15, lgrp = l >> 4;
  const int wm = w >> 2, wn = w & 3;

  const int orig = blockIdx.x;          // 0..383
  const int xcd = orig & 7;
  const int slot = orig >> 3;           // 0..47
  const int nz = slot >> 2;             // 0..11
  const int mtile = (xcd * 4 + (slot & 3)) * QBM;
  const int ntile = (nz & 3) * QBN;
  const int z = nz >> 2;

  const unsigned short* Wz = Wbf + (long long)z * H_ * H_;

  const int srow = l >> 3;
  const int sslot = l & 7;
  auto stageReg = [&](char* buf, int region, int half, int k0) {
    #pragma unroll
    for (int jj = 0; jj < 2; ++jj) {
      int j = w * 2 + jj;                       // 0..15
      int row = half * 128 + j * 8 + srow;
      int so = (sslot ^ (row & 7)) * 8;
      if (region == 0)
        gld_lds16(buf + (half * 16 + j) * 1024,
                  Xbf + (long long)(mtile + row) * H_ + k0 + so);
      else
        gld_lds16(buf + REG_B + (half * 16 + j) * 1024,
                  Wz + (long long)(ntile + row) * H_ + k0 + so);
    }
  };
  auto stageOpA = [&](char* buf, int half, int k0) { stageReg(buf, (z == 2) ? 1 : 0, half, k0); };
  auto stageOpB = [&](char* buf, int half, int k0) { stageReg(buf, (z == 2) ? 0 : 1, half, k0); };

  const int offA = (z == 2) ? REG_B : 0;
  const int offB = (z == 2) ? 0 : REG_B;
  auto rdA = [&](const char* buf, int ms, int fi, int ks) -> short8 {
    int r = ms * 128 + wm * 64 + fi * 16 + lrow;
    return *(const short8*)(buf + offA + r * 128 + (((ks * 4 + lgrp) ^ (r & 7)) * 16));
  };
  auto rdB = [&](const char* buf, int ns, int fj, int ks) -> short8 {
    int r = ns * 128 + wn * 32 + fj * 16 + lrow;
    return *(const short8*)(buf + offB + r * 128 + (((ks * 4 + lgrp) ^ (r & 7)) * 16));
  };

  f32x4 acc[8][4];
  f32x4 zero = {0.f, 0.f, 0.f, 0.f};
  #pragma unroll
  for (int a = 0; a < 8; ++a)
    #pragma unroll
    for (int c = 0; c < 4; ++c) acc[a][c] = zero;

  short8 A[4][2], B0[2][2], B1[2][2];

  stageOpA(lds, 0, 0);
  stageOpB(lds, 0, 0);
  stageOpB(lds, 1, 0);
  stageOpA(lds, 1, 0);
  stageOpA(lds + BUFSZ, 0, QBK);
  SCHED0(); WAIT_VM(6); SCHED0();
  SBAR();

  #pragma unroll 1
  for (int t = 0; t < 15; ++t) {
    char* bc = lds + ((t & 1) ? BUFSZ : 0);
    char* bn = lds + ((t & 1) ? 0 : BUFSZ);
    const int k1 = (t + 1) * QBK;
    const int k2 = (t + 2) * QBK;
    const bool st2 = (t + 2 < 16);

    RD_A(bc, 0);
    RD_B(B0, bc, 0);
    stageOpB(bn, 0, k1);
    WAIT_LGKM0(); SCHED0();
    PRIO1(); MMQ(0, 0, A, B0); PRIO0();
    SCHED0(); WAIT_VM(6); SCHED0();
    SBAR();

    RD_B(B1, bc, 1);
    stageOpB(bn, 1, k1);
    WAIT_LGKM0(); SCHED0();
    PRIO1(); MMQ(0, 2, A, B1); PRIO0();
    SCHED0(); WAIT_VM(6); SCHED0();
    SBAR();

    RD_A(bc, 1);
    stageOpA(bn, 1, k1);
    WAIT_LGKM0(); SCHED0();
    PRIO1(); MMQ(4, 2, A, B1); PRIO0();
    SCHED0(); WAIT_VM(6); SCHED0();
    SBAR();

    if (st2) stageOpA(bc, 0, k2);
    PRIO1(); MMQ(4, 0, A, B0); PRIO0();
    SCHED0(); WAIT_VM(6); SCHED0();
    SBAR();
  }

  SCHED0(); WAIT_VM(0); SCHED0();
  SBAR();
  {
    char* bc = lds + BUFSZ;
    RD_A(bc, 0);
    RD_B(B0, bc, 0);
    WAIT_LGKM0(); SCHED0();
    PRIO1(); MMQ(0, 0, A, B0); PRIO0();
    RD_B(B1, bc, 1);
    WAIT_LGKM0(); SCHED0();
    PRIO1(); MMQ(0, 2, A, B1); PRIO0();
    RD_A(bc, 1);
    WAIT_LGKM0(); SCHED0();
    PRIO1(); MMQ(4, 2, A, B1); MMQ(4, 0, A, B0); PRIO0();
  }

  const float* bias = (z == 0) ? bq : (z == 1) ? bk : bv;
  if (z != 2) {
    unsigned short* O = (z == 0) ? Qo : Ko;
    #pragma unroll
    for (int nj = 0; nj < 4; ++nj) {
      int n = ntile + (nj >> 1) * 128 + wn * 32 + (nj & 1) * 16 + lrow;
      float bv_ = bias[n];
      int h = n >> 6, d = n & 63;
      #pragma unroll
      for (int mi = 0; mi < 8; ++mi)
        #pragma unroll
        for (int r = 0; r < 4; ++r) {
          int m = mtile + (mi >> 2) * 128 + wm * 64 + (mi & 3) * 16 + lgrp * 4 + r;
          float val = acc[mi][nj][r] + bv_;
          if (z == 0) val *= 0.125f * LOG2E;
          int b = m >> 10, s = m & 1023;
          O[(((long long)(b * NH_ + h)) * S_ + s) * D_ + d] = f2bf(val);
        }
    }
  } else {
    #pragma unroll
    for (int mi = 0; mi < 8; ++mi)
      #pragma unroll
      for (int r = 0; r < 4; ++r) {
        int nfull = ntile + (mi >> 2) * 128 + wm * 64 + (mi & 3) * 16 + lgrp * 4 + r;
        float bv_ = bias[nfull];
        int h = nfull >> 6, d = nfull & 63;
        #pragma unroll
        for (int nj = 0; nj < 4; ++nj) {
          int mfull = mtile + (nj >> 1) * 128 + wn * 32 + (nj & 1) * 16 + lrow;
          float val = acc[mi][nj][r] + bv_;
          int b = mfull >> 10, s = mfull & 1023;
          Vt[(((long long)(b * NH_ + h)) * D_ + d) * S_ + s] = f2bf(val);
        }
      }
  }
}

// ---------------- kernel 3: attention v4 — permlane32_swap half-exchange ---
// Same structure as R11 (32 q/wave, grid 1024, depth-1 dbuf, fixed-max
// softmax). Change: all cross-half data movement now uses
// v_permlane32_swap_b32 (gfx950 VALU cross-lane) instead of
// __shfl_xor(..,32) (ds_bpermute: LDS pipe + lgkm wait) + cndmask selects.
// (X,Y) = swap(A,B) -> X=[A.lo|B.lo], Y=[A.hi|B.hi]; with A=Wd[2ks][p],
// B=Wd[2ks+1][p] this yields fu.u[p]=X, fu.u[2+p]=Y for BOTH halves
// (verified against the select-based R11 logic lane-by-lane).
__global__ __launch_bounds__(256, 2) void attn_fused(
    const unsigned short* __restrict__ Qbf,
    const unsigned short* __restrict__ Kbf,
    const unsigned short* __restrict__ Vtb,
    const float* __restrict__ mask,
    float* __restrict__ out) {
  __shared__ char lds[2 * 16384 + 4096];      // K|V dbuf, then mask row
  char* ldsM = lds + 32768;
  const int tid = threadIdx.x, w = tid >> 6, l = tid & 63;
  const int l31 = l & 31, h = l >> 5;

  const int lid = blockIdx.x;                 // 0..1023
  const int xcd = lid & 7, k = lid >> 3;      // all 8 q-tiles of a bh -> 1 XCD
  const int bh = xcd * 16 + (k >> 3);
  const int qt = k & 7;
  const int b = bh >> 4, hd = bh & 15;
  const int q0 = qt * 128 + w * 32;

  const unsigned short* Kg = Kbf + (long long)bh * S_ * D_;
  const unsigned short* Vg = Vtb + (long long)bh * D_ * S_;
  const float* mrow = mask + b * S_;

  auto stageKV = [&](int kt, char* buf) {
    const int key0 = kt * 64;
    #pragma unroll
    for (int t = 0; t < 2; ++t) {
      int j = w * 2 + t;
      int row = j * 8 + (l >> 3);
      int so = ((l & 7) ^ (row & 7)) * 8;
      gld_lds16(buf + j * 1024,        Kg + (long long)(key0 + row) * D_ + so);
      gld_lds16(buf + 8192 + j * 1024, Vg + (long long)row * S_ + key0 + so);
    }
  };

  // ---- prologue: qf, mask pre-transform, stage tile 0
  short8 qf[4];
  #pragma unroll
  for (int ks = 0; ks < 4; ++ks)
    qf[ks] = *(const short8*)(Qbf + ((long long)bh * S_ + q0 + l31) * D_ + ks * 16 + 8 * h);
  {
    float4 mv = *(const float4*)(mrow + tid * 4);
    f32x4 mt;
    mt[0] = mv.x * LOG2E - 12.f;
    mt[1] = mv.y * LOG2E - 12.f;
    mt[2] = mv.z * LOG2E - 12.f;
    mt[3] = mv.w * LOG2E - 12.f;
    *(f32x4*)(ldsM + tid * 16) = mt;
  }
  stageKV(0, lds);
  SCHED0(); WAIT_VM(0); SCHED0();
  __syncthreads();                   // mask ds_write + tile0 published

  f32x16 acc[2];
  #pragma unroll
  for (int db = 0; db < 2; ++db)
    #pragma unroll
    for (int r = 0; r < 16; ++r) acc[db][r] = 0.f;
  float l_run = 0.f;

  #pragma unroll 1
  for (int kt = 0; kt < S_ / 64; ++kt) {
    char* ldsK = lds + (kt & 1) * 16384;
    char* ldsV = ldsK + 8192;
    const int key0 = kt * 64;
    const bool st = (kt + 1 < S_ / 64);

    if (st) stageKV(kt + 1, lds + ((kt + 1) & 1) * 16384);

    // ---- QK^T (swapped): sc[kb] = S^T block, lane owns q col l31
    f32x16 sc[2];
    #pragma unroll
    for (int kb = 0; kb < 2; ++kb)
      #pragma unroll
      for (int r = 0; r < 16; ++r) sc[kb][r] = 0.f;

    #pragma unroll
    for (int kb = 0; kb < 2; ++kb) {
      short8 kf[4];
      #pragma unroll
      for (int ks = 0; ks < 4; ++ks) {
        int row = kb * 32 + l31;
        int g = (2 * ks + h) ^ (row & 7);
        kf[ks] = *(const short8*)(ldsK + row * 128 + g * 16);
      }
      PRIO1();
      #pragma unroll
      for (int ks = 0; ks < 4; ++ks)
        sc[kb] = __builtin_amdgcn_mfma_f32_32x32x16_bf16(
            kf[ks], qf[ks], sc[kb], 0, 0, 0);
      PRIO0();
    }

    // ---- fixed-max softmax: P = exp2(sc + mpre); sum tree only
    float sv[32];
    #pragma unroll
    for (int kb = 0; kb < 2; ++kb)
      #pragma unroll
      for (int rg = 0; rg < 4; ++rg) {
        f32x4 m4 = *(const f32x4*)(ldsM + (key0 + kb * 32 + rg * 8 + 4 * h) * 4);
        #pragma unroll
        for (int c = 0; c < 4; ++c)
          sv[kb * 16 + rg * 4 + c] = EXP2(sc[kb][rg * 4 + c] + m4[c]);
      }
    {
      float r16[16];
      #pragma unroll
      for (int i = 0; i < 16; ++i) r16[i] = sv[i] + sv[i + 16];
      #pragma unroll
      for (int i = 0; i < 8; ++i) r16[i] = r16[i] + r16[i + 8];
      #pragma unroll
      for (int i = 0; i < 4; ++i) r16[i] = r16[i] + r16[i + 4];
      float ps = (r16[0] + r16[1]) + (r16[2] + r16[3]);
      float xs = ps, ys = ps;
      asm volatile("v_permlane32_swap_b32 %0, %1" : "+v"(xs), "+v"(ys));
      l_run += xs + ys;    // = ps[l31] + ps[l31+32] at every lane
    }

    // ---- pack P -> bf16 fragments via permlane32_swap half-exchange
    short8 pfrag[4];
    {
      unsigned Wd[8][2];
      #pragma unroll
      for (int j = 0; j < 8; ++j) {
        int base = (j >> 2) * 16 + (j & 3) * 4;
        asm("v_cvt_pk_bf16_f32 %0, %1, %2" : "=v"(Wd[j][0]) : "v"(sv[base + 0]), "v"(sv[base + 1]));
        asm("v_cvt_pk_bf16_f32 %0, %1, %2" : "=v"(Wd[j][1]) : "v"(sv[base + 2]), "v"(sv[base + 3]));
      }
      #pragma unroll
      for (int ks = 0; ks < 4; ++ks) {
        unsigned x0 = Wd[2 * ks][0], y0 = Wd[2 * ks + 1][0];
        unsigned x1 = Wd[2 * ks][1], y1 = Wd[2 * ks + 1][1];
        asm volatile("v_permlane32_swap_b32 %0, %1" : "+v"(x0), "+v"(y0));
        asm volatile("v_permlane32_swap_b32 %0, %1" : "+v"(x1), "+v"(y1));
        union { unsigned u[4]; short8 s; } fu;
        fu.u[0] = x0;
        fu.u[1] = x1;
        fu.u[2] = y0;
        fu.u[3] = y1;
        pfrag[ks] = fu.s;
      }
    }

    // ---- PV (swapped): acc[db] += V^T-frag x P^T-frag
    #pragma unroll
    for (int db = 0; db < 2; ++db) {
      short8 vf[4];
      #pragma unroll
      for (int ks = 0; ks < 4; ++ks) {
        int row = db * 32 + l31;
        int g = (2 * ks + h) ^ (row & 7);
        vf[ks] = *(const short8*)(ldsV + row * 128 + g * 16);
      }
      PRIO1();
      #pragma unroll
      for (int ks = 0; ks < 4; ++ks)
        acc[db] = __builtin_amdgcn_mfma_f32_32x32x16_bf16(
            vf[ks], pfrag[ks], acc[db], 0, 0, 0);
      PRIO0();
    }

    if (st) { SCHED0(); WAIT_VM(0); SCHED0(); SBAR(); }
  }

  // ---- epilogue
  {
    float inv = 1.0f / l_run;
    int q = q0 + l31;
    float* orow = out + ((long long)b * S_ + q) * H_ + hd * D_;
    #pragma unroll
    for (int db = 0; db < 2; ++db)
      #pragma unroll
      for (int rg = 0; rg < 4; ++rg) {
        f32x4 v4;
        #pragma unroll
        for (int c = 0; c < 4; ++c) v4[c] = acc[db][rg * 4 + c] * inv;
        *(f32x4*)(orow + db * 32 + rg * 8 + 4 * h) = v4;
      }
  }
}

// ---------------- launcher -------------------------------------------------
extern "C" void kernel_launch(void* const* d_in, const int* in_sizes, int n_in,
                              void* d_out, int out_size, void* d_ws, size_t ws_size,
                              hipStream_t stream) {
  const float* X    = (const float*)d_in[0];
  const float* mask = (const float*)d_in[1];
  const float* Wq   = (const float*)d_in[2];
  const float* bq   = (const float*)d_in[3];
  const float* Wk   = (const float*)d_in[4];
  const float* bk   = (const float*)d_in[5];
  const float* Wv   = (const float*)d_in[6];
  const float* bv   = (const float*)d_in[7];
  float* out = (float*)d_out;

  char* ws = (char*)d_ws;
  unsigned short* Xbf = (unsigned short*)ws;                 // 16 MB
  unsigned short* Wbf = (unsigned short*)(ws + 16777216);    //  6 MB
  unsigned short* Qb  = (unsigned short*)(ws + 23068672);    // 16 MB
  unsigned short* Kb  = (unsigned short*)(ws + 39845888);    // 16 MB
  unsigned short* Vt  = (unsigned short*)(ws + 56623104);    // 16 MB

  hipLaunchKernelGGL(cvt_f32_bf16, dim3(2048), dim3(256), 0, stream,
                     X, Wq, Wk, Wv, Xbf, Wbf);
  hipLaunchKernelGGL(qkv_gemm, dim3(384), dim3(512), 0, stream,
                     Xbf, Wbf, bq, bk, bv, Qb, Kb, Vt);
  hipLaunchKernelGGL(attn_fused, dim3(1024), dim3(256), 0, stream,
                     Qb, Kb, Vt, mask, out);
}

// Round 13
// 117.191 us; speedup vs baseline: 2.6788x; 1.0182x over previous
//
#include <hip/hip_runtime.h>
#include <hip/hip_bf16.h>
#include <stdint.h>

#define B_ 8
#define S_ 1024
#define NH_ 16
#define D_ 64
#define H_ 1024
#define M_TOT (B_*S_)
#define LOG2E 1.44269504088896f

typedef __attribute__((ext_vector_type(8))) short short8;
typedef __attribute__((ext_vector_type(4))) float f32x4;
typedef __attribute__((ext_vector_type(16))) float f32x16;

#if __has_builtin(__builtin_amdgcn_exp2f)
#define EXP2(x) __builtin_amdgcn_exp2f(x)
#else
#define EXP2(x) __expf((x) * 0.69314718056f)
#endif

static __device__ __forceinline__ unsigned short f2bf(float f) {
  union { float f; unsigned u; } c; c.f = f;
  unsigned u = c.u;
  return (unsigned short)((u + 0x7fffu + ((u >> 16) & 1u)) >> 16);
}

static __device__ __forceinline__ void gld_lds16(void* lds, const void* g) {
  __builtin_amdgcn_global_load_lds((const __attribute__((address_space(1))) unsigned*)g,
                                   (__attribute__((address_space(3))) unsigned*)lds, 16, 0, 0);
}

#define WAIT_LGKM0() asm volatile("s_waitcnt lgkmcnt(0)" ::: "memory")
#define WAIT_VM(n)   asm volatile("s_waitcnt vmcnt(" #n ")" ::: "memory")
#define SBAR()       __builtin_amdgcn_s_barrier()
#define SCHED0()     __builtin_amdgcn_sched_barrier(0)
#define PRIO1()      __builtin_amdgcn_s_setprio(1)
#define PRIO0()      __builtin_amdgcn_s_setprio(0)

// ---------------- kernel 1: f32 -> bf16 conversion (X and the 3 weights) ----
__global__ void cvt_f32_bf16(const float* __restrict__ X,
                             const float* __restrict__ Wq,
                             const float* __restrict__ Wk,
                             const float* __restrict__ Wv,
                             unsigned short* __restrict__ Xbf,
                             unsigned short* __restrict__ Wbf) {
  const long long NX = (long long)M_TOT * H_;
  const long long NW = (long long)H_ * H_;
  long long t = (long long)blockIdx.x * blockDim.x + threadIdx.x;
  const long long stride = (long long)gridDim.x * blockDim.x;
  const long long total4 = (NX + 3 * NW) >> 2;
  for (; t < total4; t += stride) {
    long long e = t << 2;
    const float* src; unsigned short* dst;
    if (e < NX) { src = X + e; dst = Xbf + e; }
    else {
      long long r = e - NX;
      int w = (int)(r / NW);
      long long o = r - (long long)w * NW;
      src = (w == 0 ? Wq : (w == 1 ? Wk : Wv)) + o;
      dst = Wbf + (long long)w * NW + o;
    }
    float4 v = *(const float4*)src;
    ushort4 u;
    u.x = f2bf(v.x); u.y = f2bf(v.y); u.z = f2bf(v.z); u.w = f2bf(v.w);
    *(ushort4*)dst = u;
  }
}

// ---------------- shared GEMM macros (R9-verified) --------------------------
#define QBM 256
#define QBN 256
#define QBK 64
#define REG_B 32768
#define BUFSZ 65536
#define VBUF  49152

#define MMQ(I0, J0, AF, BF)                                               \
  _Pragma("unroll")                                                       \
  for (int a_ = 0; a_ < 4; ++a_)                                          \
    _Pragma("unroll")                                                     \
    for (int b_ = 0; b_ < 2; ++b_)                                        \
      _Pragma("unroll")                                                   \
      for (int k_ = 0; k_ < 2; ++k_)                                      \
        acc[(I0) + a_][(J0) + b_] = __builtin_amdgcn_mfma_f32_16x16x32_bf16( \
            AF[a_][k_], BF[b_][k_], acc[(I0) + a_][(J0) + b_], 0, 0, 0);

#define RD_A(BUF, MS)                                                     \
  _Pragma("unroll")                                                       \
  for (int f_ = 0; f_ < 4; ++f_)                                          \
    _Pragma("unroll")                                                     \
    for (int k_ = 0; k_ < 2; ++k_) A[f_][k_] = rdA(BUF, MS, f_, k_);

#define RD_B(DST, BUF, NS)                                                \
  _Pragma("unroll")                                                       \
  for (int f_ = 0; f_ < 2; ++f_)                                          \
    _Pragma("unroll")                                                     \
    for (int k_ = 0; k_ < 2; ++k_) DST[f_][k_] = rdB(BUF, NS, f_, k_);

// ---------------- kernel 2a: Q+K GEMM — 256 full 256^2 tiles, one round ----
// R9 schedule verbatim, z in {0,1} only (no operand swap).
__global__ __launch_bounds__(512, 1) void qkv_gemm_qk(
    const unsigned short* __restrict__ Xbf,
    const unsigned short* __restrict__ Wbf,
    const float* __restrict__ bq, const float* __restrict__ bk,
    unsigned short* __restrict__ Qo, unsigned short* __restrict__ Ko) {
  __shared__ char lds[2 * BUFSZ];   // 128 KB

  const int tid = threadIdx.x;
  const int w = tid >> 6;
  const int l = tid & 63;
  const int lrow = l & 15, lgrp = l >> 4;
  const int wm = w >> 2, wn = w & 3;

  const int orig = blockIdx.x;          // 0..255
  const int xcd = orig & 7;
  const int slot = orig >> 3;           // 0..31
  const int nz = slot >> 2;             // 0..7
  const int mtile = (xcd * 4 + (slot & 3)) * QBM;
  const int ntile = (nz & 3) * QBN;
  const int z = nz >> 2;                // 0..1

  const unsigned short* Wz = Wbf + (long long)z * H_ * H_;

  const int srow = l >> 3;
  const int sslot = l & 7;
  auto stageOpA = [&](char* buf, int half, int k0) {
    #pragma unroll
    for (int jj = 0; jj < 2; ++jj) {
      int j = w * 2 + jj;
      int row = half * 128 + j * 8 + srow;
      int so = (sslot ^ (row & 7)) * 8;
      gld_lds16(buf + (half * 16 + j) * 1024,
                Xbf + (long long)(mtile + row) * H_ + k0 + so);
    }
  };
  auto stageOpB = [&](char* buf, int half, int k0) {
    #pragma unroll
    for (int jj = 0; jj < 2; ++jj) {
      int j = w * 2 + jj;
      int row = half * 128 + j * 8 + srow;
      int so = (sslot ^ (row & 7)) * 8;
      gld_lds16(buf + REG_B + (half * 16 + j) * 1024,
                Wz + (long long)(ntile + row) * H_ + k0 + so);
    }
  };

  auto rdA = [&](const char* buf, int ms, int fi, int ks) -> short8 {
    int r = ms * 128 + wm * 64 + fi * 16 + lrow;
    return *(const short8*)(buf + r * 128 + (((ks * 4 + lgrp) ^ (r & 7)) * 16));
  };
  auto rdB = [&](const char* buf, int ns, int fj, int ks) -> short8 {
    int r = ns * 128 + wn * 32 + fj * 16 + lrow;
    return *(const short8*)(buf + REG_B + r * 128 + (((ks * 4 + lgrp) ^ (r & 7)) * 16));
  };

  f32x4 acc[8][4];
  f32x4 zero = {0.f, 0.f, 0.f, 0.f};
  #pragma unroll
  for (int a = 0; a < 8; ++a)
    #pragma unroll
    for (int c = 0; c < 4; ++c) acc[a][c] = zero;

  short8 A[4][2], B0[2][2], B1[2][2];

  stageOpA(lds, 0, 0);
  stageOpB(lds, 0, 0);
  stageOpB(lds, 1, 0);
  stageOpA(lds, 1, 0);
  stageOpA(lds + BUFSZ, 0, QBK);
  SCHED0(); WAIT_VM(6); SCHED0();
  SBAR();

  #pragma unroll 1
  for (int t = 0; t < 15; ++t) {
    char* bc = lds + ((t & 1) ? BUFSZ : 0);
    char* bn = lds + ((t & 1) ? 0 : BUFSZ);
    const int k1 = (t + 1) * QBK;
    const int k2 = (t + 2) * QBK;
    const bool st2 = (t + 2 < 16);

    RD_A(bc, 0);
    RD_B(B0, bc, 0);
    stageOpB(bn, 0, k1);
    WAIT_LGKM0(); SCHED0();
    PRIO1(); MMQ(0, 0, A, B0); PRIO0();
    SCHED0(); WAIT_VM(6); SCHED0();
    SBAR();

    RD_B(B1, bc, 1);
    stageOpB(bn, 1, k1);
    WAIT_LGKM0(); SCHED0();
    PRIO1(); MMQ(0, 2, A, B1); PRIO0();
    SCHED0(); WAIT_VM(6); SCHED0();
    SBAR();

    RD_A(bc, 1);
    stageOpA(bn, 1, k1);
    WAIT_LGKM0(); SCHED0();
    PRIO1(); MMQ(4, 2, A, B1); PRIO0();
    SCHED0(); WAIT_VM(6); SCHED0();
    SBAR();

    if (st2) stageOpA(bc, 0, k2);
    PRIO1(); MMQ(4, 0, A, B0); PRIO0();
    SCHED0(); WAIT_VM(6); SCHED0();
    SBAR();
  }

  SCHED0(); WAIT_VM(0); SCHED0();
  SBAR();
  {
    char* bc = lds + BUFSZ;
    RD_A(bc, 0);
    RD_B(B0, bc, 0);
    WAIT_LGKM0(); SCHED0();
    PRIO1(); MMQ(0, 0, A, B0); PRIO0();
    RD_B(B1, bc, 1);
    WAIT_LGKM0(); SCHED0();
    PRIO1(); MMQ(0, 2, A, B1); PRIO0();
    RD_A(bc, 1);
    WAIT_LGKM0(); SCHED0();
    PRIO1(); MMQ(4, 2, A, B1); MMQ(4, 0, A, B0); PRIO0();
  }

  const float* bias = (z == 0) ? bq : bk;
  unsigned short* O = (z == 0) ? Qo : Ko;
  #pragma unroll
  for (int nj = 0; nj < 4; ++nj) {
    int n = ntile + (nj >> 1) * 128 + wn * 32 + (nj & 1) * 16 + lrow;
    float bv_ = bias[n];
    int h = n >> 6, d = n & 63;
    #pragma unroll
    for (int mi = 0; mi < 8; ++mi)
      #pragma unroll
      for (int r = 0; r < 4; ++r) {
        int m = mtile + (mi >> 2) * 128 + wm * 64 + (mi & 3) * 16 + lgrp * 4 + r;
        float val = acc[mi][nj][r] + bv_;
        if (z == 0) val *= 0.125f * LOG2E;
        int b = m >> 10, s = m & 1023;
        O[(((long long)(b * NH_ + h)) * S_ + s) * D_ + d] = f2bf(val);
      }
  }
}

// ---------------- kernel 2b: V GEMM — 256 half-tiles (W 256 x X 128) -------
// Same verified fragment/epilogue math as R9's z==2 path; ns=1 phases
// deleted (2 phases/K-tile, 16 MFMA each); depth-2 staging, 3 x 48KB bufs.
// Per-tile per-thread issues: W half0+half1 (4) at P1, X (2) at P2; uniform
// vmcnt(6) -> every half is waited >=2 phases after issue; vmcnt(0) at t=14
// covers the tail.
__global__ __launch_bounds__(512, 1) void qkv_gemm_v(
    const unsigned short* __restrict__ Xbf,
    const unsigned short* __restrict__ Wbf,
    const float* __restrict__ bv,
    unsigned short* __restrict__ Vt) {
  __shared__ char lds[3 * VBUF];   // 144 KB

  const int tid = threadIdx.x;
  const int w = tid >> 6;
  const int l = tid & 63;
  const int lrow = l & 15, lgrp = l >> 4;
  const int wm = w >> 2, wn = w & 3;

  const int orig = blockIdx.x;          // 0..255
  const int xcd = orig & 7;
  const int slot = orig >> 3;           // 0..31
  const int mtile = (xcd * 8 + (slot & 7)) * 128;   // 64 m-half-tiles
  const int ntile = (slot >> 3) * QBN;              // 4 n-tiles

  const unsigned short* Wz = Wbf + 2LL * H_ * H_;

  const int srow = l >> 3;
  const int sslot = l & 7;
  auto stageW = [&](char* buf, int half, int k0) {
    #pragma unroll
    for (int jj = 0; jj < 2; ++jj) {
      int j = w * 2 + jj;
      int row = half * 128 + j * 8 + srow;
      int so = (sslot ^ (row & 7)) * 8;
      gld_lds16(buf + (half * 16 + j) * 1024,
                Wz + (long long)(ntile + row) * H_ + k0 + so);
    }
  };
  auto stageX = [&](char* buf, int k0) {
    #pragma unroll
    for (int jj = 0; jj < 2; ++jj) {
      int j = w * 2 + jj;
      int row = j * 8 + srow;
      int so = (sslot ^ (row & 7)) * 8;
      gld_lds16(buf + 32768 + j * 1024,
                Xbf + (long long)(mtile + row) * H_ + k0 + so);
    }
  };

  auto rdA = [&](const char* buf, int ms, int fi, int ks) -> short8 {  // W
    int r = ms * 128 + wm * 64 + fi * 16 + lrow;
    return *(const short8*)(buf + r * 128 + (((ks * 4 + lgrp) ^ (r & 7)) * 16));
  };
  auto rdB = [&](const char* buf, int ns, int fj, int ks) -> short8 {  // X
    int r = wn * 32 + fj * 16 + lrow;
    (void)ns;
    return *(const short8*)(buf + 32768 + r * 128 + (((ks * 4 + lgrp) ^ (r & 7)) * 16));
  };

  f32x4 acc[8][2];
  f32x4 zero = {0.f, 0.f, 0.f, 0.f};
  #pragma unroll
  for (int a = 0; a < 8; ++a)
    #pragma unroll
    for (int c = 0; c < 2; ++c) acc[a][c] = zero;

  short8 A[4][2], B0[2][2];

  // prologue: stage tiles 0 (buf0) and 1 (buf1), 6 issues each
  stageW(lds, 0, 0); stageW(lds, 1, 0); stageX(lds, 0);
  stageW(lds + VBUF, 0, QBK); stageW(lds + VBUF, 1, QBK); stageX(lds + VBUF, QBK);
  SCHED0(); WAIT_VM(6); SCHED0();    // tile 0 resident, tile 1 in flight
  SBAR();

  #pragma unroll 1
  for (int t = 0; t < 16; ++t) {
    char* bc = lds + (t % 3) * VBUF;
    char* b2 = lds + ((t + 2) % 3) * VBUF;
    const int k2 = (t + 2) * QBK;
    const bool st2 = (t + 2 < 16);

    // ---- P1: read W(ms0) + X; stage W(t+2); MFMA upper half
    RD_A(bc, 0);
    RD_B(B0, bc, 0);
    if (st2) { stageW(b2, 0, k2); stageW(b2, 1, k2); }
    WAIT_LGKM0(); SCHED0();
    PRIO1(); MMQ(0, 0, A, B0); PRIO0();
    SCHED0(); WAIT_VM(6); SCHED0();
    SBAR();

    // ---- P2: read W(ms1); stage X(t+2); MFMA lower half
    RD_A(bc, 1);
    if (st2) stageX(b2, k2);
    WAIT_LGKM0(); SCHED0();
    PRIO1(); MMQ(4, 0, A, B0); PRIO0();
    SCHED0();
    if (t < 14) { WAIT_VM(6); } else { WAIT_VM(0); }
    SCHED0();
    SBAR();
  }

  // ---- epilogue (R9 z==2 path, nj restricted to ns=0)
  #pragma unroll
  for (int mi = 0; mi < 8; ++mi)
    #pragma unroll
    for (int r = 0; r < 4; ++r) {
      int nfull = ntile + (mi >> 2) * 128 + wm * 64 + (mi & 3) * 16 + lgrp * 4 + r;
      float bv_ = bv[nfull];
      int h = nfull >> 6, d = nfull & 63;
      #pragma unroll
      for (int nj = 0; nj < 2; ++nj) {
        int mfull = mtile + wn * 32 + nj * 16 + lrow;
        float val = acc[mi][nj][r] + bv_;
        int b = mfull >> 10, s = mfull & 1023;
        Vt[(((long long)(b * NH_ + h)) * D_ + d) * S_ + s] = f2bf(val);
      }
    }
}

// ---------------- kernel 3: attention (R12 verbatim — permlane32_swap) -----
__global__ __launch_bounds__(256, 2) void attn_fused(
    const unsigned short* __restrict__ Qbf,
    const unsigned short* __restrict__ Kbf,
    const unsigned short* __restrict__ Vtb,
    const float* __restrict__ mask,
    float* __restrict__ out) {
  __shared__ char lds[2 * 16384 + 4096];      // K|V dbuf, then mask row
  char* ldsM = lds + 32768;
  const int tid = threadIdx.x, w = tid >> 6, l = tid & 63;
  const int l31 = l & 31, h = l >> 5;

  const int lid = blockIdx.x;                 // 0..1023
  const int xcd = lid & 7, k = lid >> 3;      // all 8 q-tiles of a bh -> 1 XCD
  const int bh = xcd * 16 + (k >> 3);
  const int qt = k & 7;
  const int b = bh >> 4, hd = bh & 15;
  const int q0 = qt * 128 + w * 32;

  const unsigned short* Kg = Kbf + (long long)bh * S_ * D_;
  const unsigned short* Vg = Vtb + (long long)bh * D_ * S_;
  const float* mrow = mask + b * S_;

  auto stageKV = [&](int kt, char* buf) {
    const int key0 = kt * 64;
    #pragma unroll
    for (int t = 0; t < 2; ++t) {
      int j = w * 2 + t;
      int row = j * 8 + (l >> 3);
      int so = ((l & 7) ^ (row & 7)) * 8;
      gld_lds16(buf + j * 1024,        Kg + (long long)(key0 + row) * D_ + so);
      gld_lds16(buf + 8192 + j * 1024, Vg + (long long)row * S_ + key0 + so);
    }
  };

  short8 qf[4];
  #pragma unroll
  for (int ks = 0; ks < 4; ++ks)
    qf[ks] = *(const short8*)(Qbf + ((long long)bh * S_ + q0 + l31) * D_ + ks * 16 + 8 * h);
  {
    float4 mv = *(const float4*)(mrow + tid * 4);
    f32x4 mt;
    mt[0] = mv.x * LOG2E - 12.f;
    mt[1] = mv.y * LOG2E - 12.f;
    mt[2] = mv.z * LOG2E - 12.f;
    mt[3] = mv.w * LOG2E - 12.f;
    *(f32x4*)(ldsM + tid * 16) = mt;
  }
  stageKV(0, lds);
  SCHED0(); WAIT_VM(0); SCHED0();
  __syncthreads();

  f32x16 acc[2];
  #pragma unroll
  for (int db = 0; db < 2; ++db)
    #pragma unroll
    for (int r = 0; r < 16; ++r) acc[db][r] = 0.f;
  float l_run = 0.f;

  #pragma unroll 1
  for (int kt = 0; kt < S_ / 64; ++kt) {
    char* ldsK = lds + (kt & 1) * 16384;
    char* ldsV = ldsK + 8192;
    const int key0 = kt * 64;
    const bool st = (kt + 1 < S_ / 64);

    if (st) stageKV(kt + 1, lds + ((kt + 1) & 1) * 16384);

    f32x16 sc[2];
    #pragma unroll
    for (int kb = 0; kb < 2; ++kb)
      #pragma unroll
      for (int r = 0; r < 16; ++r) sc[kb][r] = 0.f;

    #pragma unroll
    for (int kb = 0; kb < 2; ++kb) {
      short8 kf[4];
      #pragma unroll
      for (int ks = 0; ks < 4; ++ks) {
        int row = kb * 32 + l31;
        int g = (2 * ks + h) ^ (row & 7);
        kf[ks] = *(const short8*)(ldsK + row * 128 + g * 16);
      }
      PRIO1();
      #pragma unroll
      for (int ks = 0; ks < 4; ++ks)
        sc[kb] = __builtin_amdgcn_mfma_f32_32x32x16_bf16(
            kf[ks], qf[ks], sc[kb], 0, 0, 0);
      PRIO0();
    }

    float sv[32];
    #pragma unroll
    for (int kb = 0; kb < 2; ++kb)
      #pragma unroll
      for (int rg = 0; rg < 4; ++rg) {
        f32x4 m4 = *(const f32x4*)(ldsM + (key0 + kb * 32 + rg * 8 + 4 * h) * 4);
        #pragma unroll
        for (int c = 0; c < 4; ++c)
          sv[kb * 16 + rg * 4 + c] = EXP2(sc[kb][rg * 4 + c] + m4[c]);
      }
    {
      float r16[16];
      #pragma unroll
      for (int i = 0; i < 16; ++i) r16[i] = sv[i] + sv[i + 16];
      #pragma unroll
      for (int i = 0; i < 8; ++i) r16[i] = r16[i] + r16[i + 8];
      #pragma unroll
      for (int i = 0; i < 4; ++i) r16[i] = r16[i] + r16[i + 4];
      float ps = (r16[0] + r16[1]) + (r16[2] + r16[3]);
      float xs = ps, ys = ps;
      asm volatile("v_permlane32_swap_b32 %0, %1" : "+v"(xs), "+v"(ys));
      l_run += xs + ys;
    }

    short8 pfrag[4];
    {
      unsigned Wd[8][2];
      #pragma unroll
      for (int j = 0; j < 8; ++j) {
        int base = (j >> 2) * 16 + (j & 3) * 4;
        asm("v_cvt_pk_bf16_f32 %0, %1, %2" : "=v"(Wd[j][0]) : "v"(sv[base + 0]), "v"(sv[base + 1]));
        asm("v_cvt_pk_bf16_f32 %0, %1, %2" : "=v"(Wd[j][1]) : "v"(sv[base + 2]), "v"(sv[base + 3]));
      }
      #pragma unroll
      for (int ks = 0; ks < 4; ++ks) {
        unsigned x0 = Wd[2 * ks][0], y0 = Wd[2 * ks + 1][0];
        unsigned x1 = Wd[2 * ks][1], y1 = Wd[2 * ks + 1][1];
        asm volatile("v_permlane32_swap_b32 %0, %1" : "+v"(x0), "+v"(y0));
        asm volatile("v_permlane32_swap_b32 %0, %1" : "+v"(x1), "+v"(y1));
        union { unsigned u[4]; short8 s; } fu;
        fu.u[0] = x0;
        fu.u[1] = x1;
        fu.u[2] = y0;
        fu.u[3] = y1;
        pfrag[ks] = fu.s;
      }
    }

    #pragma unroll
    for (int db = 0; db < 2; ++db) {
      short8 vf[4];
      #pragma unroll
      for (int ks = 0; ks < 4; ++ks) {
        int row = db * 32 + l31;
        int g = (2 * ks + h) ^ (row & 7);
        vf[ks] = *(const short8*)(ldsV + row * 128 + g * 16);
      }
      PRIO1();
      #pragma unroll
      for (int ks = 0; ks < 4; ++ks)
        acc[db] = __builtin_amdgcn_mfma_f32_32x32x16_bf16(
            vf[ks], pfrag[ks], acc[db], 0, 0, 0);
      PRIO0();
    }

    if (st) { SCHED0(); WAIT_VM(0); SCHED0(); SBAR(); }
  }

  {
    float inv = 1.0f / l_run;
    int q = q0 + l31;
    float* orow = out + ((long long)b * S_ + q) * H_ + hd * D_;
    #pragma unroll
    for (int db = 0; db < 2; ++db)
      #pragma unroll
      for (int rg = 0; rg < 4; ++rg) {
        f32x4 v4;
        #pragma unroll
        for (int c = 0; c < 4; ++c) v4[c] = acc[db][rg * 4 + c] * inv;
        *(f32x4*)(orow + db * 32 + rg * 8 + 4 * h) = v4;
      }
  }
}

// ---------------- launcher -------------------------------------------------
extern "C" void kernel_launch(void* const* d_in, const int* in_sizes, int n_in,
                              void* d_out, int out_size, void* d_ws, size_t ws_size,
                              hipStream_t stream) {
  const float* X    = (const float*)d_in[0];
  const float* mask = (const float*)d_in[1];
  const float* Wq   = (const float*)d_in[2];
  const float* bq   = (const float*)d_in[3];
  const float* Wk   = (const float*)d_in[4];
  const float* bk   = (const float*)d_in[5];
  const float* Wv   = (const float*)d_in[6];
  const float* bv   = (const float*)d_in[7];
  float* out = (float*)d_out;

  char* ws = (char*)d_ws;
  unsigned short* Xbf = (unsigned short*)ws;                 // 16 MB
  unsigned short* Wbf = (unsigned short*)(ws + 16777216);    //  6 MB
  unsigned short* Qb  = (unsigned short*)(ws + 23068672);    // 16 MB
  unsigned short* Kb  = (unsigned short*)(ws + 39845888);    // 16 MB
  unsigned short* Vt  = (unsigned short*)(ws + 56623104);    // 16 MB

  hipLaunchKernelGGL(cvt_f32_bf16, dim3(2048), dim3(256), 0, stream,
                     X, Wq, Wk, Wv, Xbf, Wbf);
  hipLaunchKernelGGL(qkv_gemm_qk, dim3(256), dim3(512), 0, stream,
                     Xbf, Wbf, bq, bk, Qb, Kb);
  hipLaunchKernelGGL(qkv_gemm_v, dim3(256), dim3(512), 0, stream,
                     Xbf, Wbf, bv, Vt);
  hipLaunchKernelGGL(attn_fused, dim3(1024), dim3(256), 0, stream,
                     Qb, Kb, Vt, mask, out);
}